// Round 1
// baseline (316.511 us; speedup 1.0000x reference)
//
#include <hip/hip_runtime.h>

// Problem constants (match reference setup_inputs)
constexpr int B_  = 256;   // students
constexpr int T_  = 200;   // max_step
constexpr int Q_  = 1000;  // questions
constexpr int TM1 = T_ - 1;        // 199 steps per student
constexpr int NBT = B_ * TM1;      // 50944

// ---- wave (64-lane) reductions ----
__device__ inline float waveReduceSum(float v) {
#pragma unroll
    for (int off = 32; off > 0; off >>= 1)
        v += __shfl_down(v, off, 64);
    return v;
}
__device__ inline int waveReduceMax(int v) {
#pragma unroll
    for (int off = 32; off > 0; off >>= 1)
        v = max(v, __shfl_down(v, off, 64));
    return v;
}

// One block per student s. Thread tid handles step i = tid (tid < TM1).
//   pc[s,i] = sigmoid(logit_c[s, i, q_idx[s, i+1]])
//   a[s,i]  = correct[s, i+1]
// mask: keep i <= last, last = max{i : pc>0} (or T-2 if none), count = last+1
// BCE with log clamped at -100; per-student mean; partial loss -> ws[s].
// p_mean and ground_truth written directly to out[1..].
__global__ __launch_bounds__(256)
void student_kernel(const float* __restrict__ logit_c,
                    const float* __restrict__ logit_t,
                    const int*   __restrict__ q_idx,
                    const int*   __restrict__ correct,
                    float*       __restrict__ out,   // [1 + 2*NBT]
                    float*       __restrict__ ws)    // [B_] per-student loss
{
    const int s    = blockIdx.x;
    const int tid  = threadIdx.x;
    const int wave = tid >> 6;
    const int lane = tid & 63;

    __shared__ int   smax[4];
    __shared__ float ssum[4][2];
    __shared__ int   s_last;

    float pc = 0.f, pt = 0.f, a = 0.f;
    if (tid < TM1) {
        const int base = s * T_ + tid;          // (s, step tid)
        const int q    = q_idx[base + 1];       // q_idx[s, tid+1]
        a = (float)correct[base + 1];           // correct[s, tid+1]
        const float lc = logit_c[(size_t)base * Q_ + q];
        const float lt = logit_t[(size_t)base * Q_ + q];
        pc = 1.0f / (1.0f + expf(-lc));
        pt = 1.0f / (1.0f + expf(-lt));
    }

    // last valid index (pc > 0), reference semantics: all-false -> T-2
    int vi = (tid < TM1 && pc > 0.0f) ? tid : -1;
    vi = waveReduceMax(vi);
    if (lane == 0) smax[wave] = vi;
    __syncthreads();
    if (tid == 0) {
        int m = max(max(smax[0], smax[1]), max(smax[2], smax[3]));
        s_last = (m < 0) ? (T_ - 2) : m;
    }
    __syncthreads();
    const int   last  = s_last;
    const float count = (float)(last + 1);

    float ec = 0.f, et = 0.f;
    if (tid < TM1 && tid <= last) {
        const float lp_c = fmaxf(logf(pc),     -100.0f);
        const float l1_c = fmaxf(log1pf(-pc),  -100.0f);
        const float lp_t = fmaxf(logf(pt),     -100.0f);
        const float l1_t = fmaxf(log1pf(-pt),  -100.0f);
        ec = -(a * lp_c + (1.0f - a) * l1_c);
        et = -(a * lp_t + (1.0f - a) * l1_t);
    }
    float ecs = waveReduceSum(ec);
    float ets = waveReduceSum(et);
    if (lane == 0) { ssum[wave][0] = ecs; ssum[wave][1] = ets; }
    __syncthreads();
    if (tid == 0) {
        const float tc = ssum[0][0] + ssum[1][0] + ssum[2][0] + ssum[3][0];
        const float tt = ssum[0][1] + ssum[1][1] + ssum[2][1] + ssum[3][1];
        ws[s] = tt / count + tc / count;   // bce_mean(pt) + bce_mean(pc)
    }

    if (tid < TM1) {
        out[1 + s * TM1 + tid]       = 0.5f * (pt + pc);  // p_mean
        out[1 + NBT + s * TM1 + tid] = a;                 // ground_truth
    }
}

// Deterministic final sum of the 256 per-student losses -> out[0].
__global__ __launch_bounds__(256)
void final_reduce(const float* __restrict__ ws, float* __restrict__ out)
{
    const int tid = threadIdx.x;
    __shared__ float sp[4];
    float w = waveReduceSum(ws[tid]);
    if ((tid & 63) == 0) sp[tid >> 6] = w;
    __syncthreads();
    if (tid == 0) out[0] = sp[0] + sp[1] + sp[2] + sp[3];
}

extern "C" void kernel_launch(void* const* d_in, const int* in_sizes, int n_in,
                              void* d_out, int out_size, void* d_ws, size_t ws_size,
                              hipStream_t stream)
{
    const float* logit_c = (const float*)d_in[0];
    const float* logit_t = (const float*)d_in[1];
    const int*   q_idx   = (const int*)d_in[2];
    const int*   correct = (const int*)d_in[3];
    float* out = (float*)d_out;
    float* ws  = (float*)d_ws;   // needs B_ floats = 1 KiB

    hipLaunchKernelGGL(student_kernel, dim3(B_), dim3(256), 0, stream,
                       logit_c, logit_t, q_idx, correct, out, ws);
    hipLaunchKernelGGL(final_reduce, dim3(1), dim3(256), 0, stream, ws, out);
}